// Round 12
// baseline (728.153 us; speedup 1.0000x reference)
//
#include <hip/hip_runtime.h>

typedef unsigned short u16;
typedef __attribute__((ext_vector_type(8))) short short8;
typedef __attribute__((ext_vector_type(4))) float f32x4;

#define MFMA_BF16 __builtin_amdgcn_mfma_f32_16x16x32_bf16

__device__ __forceinline__ u16 f2bf(float f){
  unsigned int u = __builtin_bit_cast(unsigned int, f);
  u += 0x7fffu + ((u >> 16) & 1u);
  return (u16)(u >> 16);
}

// async global->LDS 16B: lane i writes lds_base + i*16
__device__ __forceinline__ void gld16(const void* g, void* l){
  __builtin_amdgcn_global_load_lds(
      (const __attribute__((address_space(1))) unsigned int*)g,
      (__attribute__((address_space(3))) unsigned int*)l, 16, 0, 0);
}

// ---------------- batched fp32 transposes of the 4 weights ----------------
// z=0: Wdq (256x1024)->wdqT ; z=1..3: Wuq/Wuk/Wuv (1024x256)->T
__global__ void k_transpose4(const float* __restrict__ s0, float* __restrict__ d0,
                             const float* __restrict__ s1, float* __restrict__ d1,
                             const float* __restrict__ s2, float* __restrict__ d2,
                             const float* __restrict__ s3, float* __restrict__ d3)
{
  __shared__ float tile[32][33];
  int z = blockIdx.z;
  const float* src = z == 0 ? s0 : z == 1 ? s1 : z == 2 ? s2 : s3;
  float* dst       = z == 0 ? d0 : z == 1 ? d1 : z == 2 ? d2 : d3;
  int rows = z == 0 ? 256 : 1024, cols = z == 0 ? 1024 : 256;
  int c0 = blockIdx.x * 32, r0 = blockIdx.y * 32;
  if (c0 >= cols || r0 >= rows) return;
  int tx = threadIdx.x, ty = threadIdx.y;
#pragma unroll
  for (int i = 0; i < 4; ++i){
    int r = ty + i * 8;
    tile[r][tx] = src[(long)(r0 + r) * cols + c0 + tx];
  }
  __syncthreads();
#pragma unroll
  for (int i = 0; i < 4; ++i){
    int r = ty + i * 8;
    dst[(long)(c0 + r) * rows + r0 + tx] = tile[tx][r];
  }
}

// ---------------- NT MFMA GEMM: C[M,N] = scale * A[M,K] * B[N,K]^T ----------------
__global__ __launch_bounds__(256)
void k_gemm_nt(const float* __restrict__ A, const float* __restrict__ B,
               float* __restrict__ Cf, u16* __restrict__ Cb,
               int M, int N, int K, int lda, int ldb, int ldc,
               long sA, long sB, long sC, float scale)
{
  A += (long)blockIdx.z * sA; B += (long)blockIdx.z * sB;
  if (Cf) Cf += (long)blockIdx.z * sC;
  if (Cb) Cb += (long)blockIdx.z * sC;
  const int n0 = blockIdx.x * 64, m0 = blockIdx.y * 64;
  const int tid = threadIdx.x;
  const int wave = tid >> 6, lane = tid & 63, quad = lane >> 4, l16 = lane & 15;
  __shared__ u16 As[64 * 40];
  __shared__ u16 Bs[64 * 40];
  f32x4 acc[4];
#pragma unroll
  for (int n = 0; n < 4; ++n) acc[n] = (f32x4){0.f, 0.f, 0.f, 0.f};

  const int lr = tid >> 2;
  const int lc = (tid & 3) * 8;
  for (int k0 = 0; k0 < K; k0 += 32){
    {
      const float* pa = &A[(long)(m0 + lr) * lda + k0 + lc];
      float4 a0 = *(const float4*)pa;
      float4 a1 = *(const float4*)(pa + 4);
      short8 pk;
      pk[0]=(short)f2bf(a0.x); pk[1]=(short)f2bf(a0.y); pk[2]=(short)f2bf(a0.z); pk[3]=(short)f2bf(a0.w);
      pk[4]=(short)f2bf(a1.x); pk[5]=(short)f2bf(a1.y); pk[6]=(short)f2bf(a1.z); pk[7]=(short)f2bf(a1.w);
      *(short8*)&As[lr * 40 + lc] = pk;
      const float* pb = &B[(long)(n0 + lr) * ldb + k0 + lc];
      float4 b0 = *(const float4*)pb;
      float4 b1 = *(const float4*)(pb + 4);
      short8 qk;
      qk[0]=(short)f2bf(b0.x); qk[1]=(short)f2bf(b0.y); qk[2]=(short)f2bf(b0.z); qk[3]=(short)f2bf(b0.w);
      qk[4]=(short)f2bf(b1.x); qk[5]=(short)f2bf(b1.y); qk[6]=(short)f2bf(b1.z); qk[7]=(short)f2bf(b1.w);
      *(short8*)&Bs[lr * 40 + lc] = qk;
    }
    __syncthreads();
    short8 a = *(const short8*)&As[(wave * 16 + l16) * 40 + quad * 8];
#pragma unroll
    for (int n = 0; n < 4; ++n){
      short8 b = *(const short8*)&Bs[(n * 16 + l16) * 40 + quad * 8];
      acc[n] = MFMA_BF16(a, b, acc[n], 0, 0, 0);
    }
    __syncthreads();
  }
#pragma unroll
  for (int n = 0; n < 4; ++n)
#pragma unroll
    for (int r = 0; r < 4; ++r){
      int row = m0 + wave * 16 + quad * 4 + r;
      int col = n0 + n * 16 + l16;
      float v = acc[n][r] * scale;
      if (Cf) Cf[(long)row * ldc + col] = v;
      if (Cb) Cb[(long)row * ldc + col] = f2bf(v);
    }
}

// ---------------- fused projections v2: xq = x@Wdq^T (bf16), ckv = x@Wdkv^T ----------------
// Round-12 (re-run of r11; bench infra failed, kernel re-audited clean):
// 32-row x 512-col blocks (BOTH weights' full width per block). Old k_proj's
// 8 column-tiles re-fetched the fp32 x 8x (~512MB traffic, est. ~85us of the
// 204us preamble). Here x is fetched exactly once (32MB); the 2MB fp32
// weights are re-read per block but L2-resident. Grid 256 blocks = full
// machine, one round. Numerics identical (same bf16-cast-then-MFMA path).
__global__ __launch_bounds__(512)
void k_proj2(const float* __restrict__ x, const float* __restrict__ Wdq,
             const float* __restrict__ Wdkv, u16* __restrict__ xq,
             float* __restrict__ ckv_f, u16* __restrict__ ckv_bf, u16* __restrict__ ckvT)
{
  const int m0 = blockIdx.x * 32;
  const int tid = threadIdx.x;
  const int w = tid >> 6, lane = tid & 63, quad = lane >> 4, l16 = lane & 15;
  const int rs = (w & 1) * 16, cq = w >> 1;    // row-strip (0/16), col-quarter (0..3)

  __shared__ u16 As[32 * 40];
  __shared__ u16 Bs[512 * 40];

  f32x4 acc[8];
#pragma unroll
  for (int n = 0; n < 8; ++n) acc[n] = (f32x4){0.f, 0.f, 0.f, 0.f};

  // staging roles: thread tid stages weight row tid (Wdq 0..255, Wdkv 256..511)
  const float* brow = (tid < 256) ? (Wdq + (long)tid * 1024)
                                  : (Wdkv + (long)(tid - 256) * 1024);
  const int ar = tid >> 4;          // 0..31  (x row)
  const int ac = (tid & 15) * 2;    // 0..30  (x col pair)

  for (int k0 = 0; k0 < 1024; k0 += 32){
    {
      float2 a2 = *(const float2*)&x[(long)(m0 + ar) * 1024 + k0 + ac];
      As[ar * 40 + ac]     = f2bf(a2.x);
      As[ar * 40 + ac + 1] = f2bf(a2.y);
#pragma unroll
      for (int q = 0; q < 4; ++q){
        float4 bv = *(const float4*)&brow[k0 + q * 8];
        float4 bw = *(const float4*)&brow[k0 + q * 8 + 4];
        short8 pk;
        pk[0]=(short)f2bf(bv.x); pk[1]=(short)f2bf(bv.y); pk[2]=(short)f2bf(bv.z); pk[3]=(short)f2bf(bv.w);
        pk[4]=(short)f2bf(bw.x); pk[5]=(short)f2bf(bw.y); pk[6]=(short)f2bf(bw.z); pk[7]=(short)f2bf(bw.w);
        *(short8*)&Bs[tid * 40 + q * 8] = pk;
      }
    }
    __syncthreads();
    short8 a = *(const short8*)&As[(rs + l16) * 40 + quad * 8];
#pragma unroll
    for (int n = 0; n < 8; ++n){
      short8 b = *(const short8*)&Bs[(cq * 128 + n * 16 + l16) * 40 + quad * 8];
      acc[n] = MFMA_BF16(a, b, acc[n], 0, 0, 0);
    }
    __syncthreads();
  }

  const int bb = m0 >> 11;
  const int t0 = (m0 & 2047) + rs + quad * 4;
#pragma unroll
  for (int n = 0; n < 8; ++n){
    int colW = cq * 128 + n * 16 + l16;
    if (colW < 256){
#pragma unroll
      for (int r = 0; r < 4; ++r){
        int row = m0 + rs + quad * 4 + r;
        xq[(long)row * 256 + colW] = f2bf(acc[n][r]);
      }
    } else {
      int c = colW - 256;
      u16 pk[4];
#pragma unroll
      for (int r = 0; r < 4; ++r){
        int row = m0 + rs + quad * 4 + r;
        float v = acc[n][r];
        ckv_f [(long)row * 256 + c] = v;
        ckv_bf[(long)row * 256 + c] = f2bf(v);
        pk[r] = f2bf(v);
      }
      *(uint2*)&ckvT[((long)bb * 256 + c) * 2048 + t0] = *(uint2*)pk;
    }
  }
}

// ---------------- fused MLA flash attention ----------------
// Round-7 version verbatim (best: 486us). QT=128, KVBLK=64, dbuf,
// 1 barrier/iter, XCD-balanced qt pairing. Register wall (r4/r5/r8/r10):
// true regs ~164/wave -> 2 waves/SIMD spill-free is this design's optimum;
// 12-wave 3/SIMD (r10) reaches occupancy 24% but the forced 168-reg cap
// spills (~50MB scratch) -> parity. Flash is at its structural floor.
__global__ __launch_bounds__(512, 2)
void k_flash(const u16* __restrict__ xq, const u16* __restrict__ Pt,
             const u16* __restrict__ ckv_bf, const u16* __restrict__ ckvT,
             const u16* __restrict__ Vt, float* __restrict__ y)
{
  const int bx = blockIdx.x;
  const int qt = (bx < 8) ? (15 - bx) : (bx - 8);   // XCD-balanced pairing
  const int h = blockIdx.y, b = blockIdx.z;
  const int tid = threadIdx.x;
  const int wg = tid >> 6, lane = tid & 63, quad = lane >> 4, l16 = lane & 15;

  // u16 layout: [0,16384) bufA0 ckv | [16384,32768) bufA1 |
  //             [32768,49152) bufB0 ckvT | [49152,65536) bufB1 |
  //             [65536,73728) per-wave P (8 x 16x64, granule-XOR swizzled)
  // [0,32768) doubles as q_lat park (128x256) in phase 0 and ctx park in epilogue.
  __shared__ u16 LDS[73728];
  u16* PW = LDS + 65536 + wg * 1024;

  const int trow = wg * 16 + l16;          // 0..127 (this lane's q-row in tile)
  const int swr  = l16 & 7;                // row-swizzle key (trow & 7 == l16 & 7)
  const long tglob = (long)b * 2048 + qt * 128;

  const u16* ckv_b  = ckv_bf + (long)b * 2048 * 256;
  const u16* ckvT_b = ckvT   + (long)b * 256 * 2048;

  // staging offsets (u16 units); wave wg stages chunks wg*4+j of each tile
  int offA[4], offB[4];
  {
    int l5 = lane >> 5, g32 = lane & 31;
#pragma unroll
    for (int j = 0; j < 4; ++j){
      int s = (wg * 4 + j) * 2 + l5;              // 0..63 (kv row)
      offA[j] = s * 256 + ((g32 ^ (s & 7)) * 8);  // pre-swizzled source granule
    }
    int l3 = lane >> 3, g8 = lane & 7;
#pragma unroll
    for (int j = 0; j < 4; ++j){
      int l = (wg * 4 + j) * 8 + l3;              // 0..255 (latent row)
      offB[j] = l * 2048 + ((g8 ^ (l & 7)) * 8);
    }
  }

  // ---- phase 0: q_lat^T = Pt[h](A) x xq(B); park in LDS[0..32768), read back aS
  short8 aS[8];
  {
    short8 bq[8];
    const u16* xr = xq + (tglob + trow) * 256;
#pragma unroll
    for (int ks = 0; ks < 8; ++ks)
      bq[ks] = *(const short8*)&xr[ks * 32 + quad * 8];
    const u16* pth = Pt + (long)h * 65536;
#pragma unroll
    for (int mb = 0; mb < 16; ++mb){
      f32x4 acc = (f32x4){0.f, 0.f, 0.f, 0.f};
#pragma unroll
      for (int ks = 0; ks < 8; ++ks){
        short8 pa = *(const short8*)&pth[(mb * 16 + l16) * 256 + ks * 32 + quad * 8];
        acc = MFMA_BF16(pa, bq[ks], acc, 0, 0, 0);
      }
#pragma unroll
      for (int r = 0; r < 4; ++r){
        int l = mb * 16 + quad * 4 + r;
        int cs = (((l >> 3) ^ swr) << 3) | (l & 7);
        LDS[trow * 256 + cs] = f2bf(acc[r]);
      }
    }
  }
  __syncthreads();                         // park visible
#pragma unroll
  for (int ks = 0; ks < 8; ++ks){
    int gl = ks * 4 + quad;
    aS[ks] = *(const short8*)&LDS[trow * 256 + ((gl ^ swr) << 3)];
  }
  __syncthreads();                         // all aS reads done; buffers reusable

  // prologue: stage tile 0 into buffer 0
#pragma unroll
  for (int j = 0; j < 4; ++j)
    gld16(ckv_b + offA[j], &LDS[(wg * 4 + j) * 512]);
#pragma unroll
  for (int j = 0; j < 4; ++j)
    gld16(ckvT_b + offB[j], &LDS[32768 + (wg * 4 + j) * 512]);

  // ---- phase 1: online-softmax KV loop (double-buffered, 1 barrier/iter)
  float m_t = -1e30f, l_t = 0.f;
  f32x4 oacc[16];
#pragma unroll
  for (int n = 0; n < 16; ++n) oacc[n] = (f32x4){0.f, 0.f, 0.f, 0.f};

  const int stmax = 2 * qt + 1;
  const int tg = qt * 128 + trow;
  for (int st = 0; st <= stmax; ++st){
    const int cur = st & 1;
    __syncthreads();   // tile st landed in buf[cur] (vmcnt drained); prev-iter
                       // reads of buf[cur^1] complete -> safe to overwrite
    if (st < stmax){
      const int nx = cur ^ 1;
#pragma unroll
      for (int j = 0; j < 4; ++j)
        gld16(ckv_b + (long)(st + 1) * 16384 + offA[j],
              &LDS[nx * 16384 + (wg * 4 + j) * 512]);
#pragma unroll
      for (int j = 0; j < 4; ++j)
        gld16(ckvT_b + (st + 1) * 64 + offB[j],
              &LDS[32768 + nx * 16384 + (wg * 4 + j) * 512]);
    }
    if (st * 64 > qt * 128 + wg * 16 + 15) continue;   // whole wave masked

    const u16* X0 = LDS + cur * 16384;
    const u16* X1 = LDS + 32768 + cur * 16384;

    // S^T = ckv(A: m=s) x q_lat(B: n=t)
    f32x4 sacc[4];
#pragma unroll
    for (int mb = 0; mb < 4; ++mb) sacc[mb] = (f32x4){0.f, 0.f, 0.f, 0.f};
    __builtin_amdgcn_s_setprio(1);
#pragma unroll
    for (int ks = 0; ks < 8; ++ks){
      int gl = ks * 4 + quad;
#pragma unroll
      for (int mb = 0; mb < 4; ++mb){
        short8 a = *(const short8*)&X0[(mb * 16 + l16) * 256 + ((gl ^ swr) << 3)];
        sacc[mb] = MFMA_BF16(a, aS[ks], sacc[mb], 0, 0, 0);
      }
    }
    __builtin_amdgcn_s_setprio(0);

    if (st * 64 + 63 > tg){   // causal mask: s > t -> -inf
#pragma unroll
      for (int mb = 0; mb < 4; ++mb)
#pragma unroll
        for (int r = 0; r < 4; ++r)
          if (st * 64 + mb * 16 + quad * 4 + r > tg) sacc[mb][r] = -1e30f;
    }

    // online softmax: per-lane state for t = trow (replicated across quads)
    float rm = sacc[0][0];
#pragma unroll
    for (int mb = 0; mb < 4; ++mb)
#pragma unroll
      for (int r = 0; r < 4; ++r) rm = fmaxf(rm, sacc[mb][r]);
    rm = fmaxf(rm, __shfl_xor(rm, 16, 64));
    rm = fmaxf(rm, __shfl_xor(rm, 32, 64));
    if (!__all(rm <= m_t + 8.f)){          // defer-max: skip rescale when growth small
      float mnew = fmaxf(m_t, rm);
      float alpha = __expf(m_t - mnew);
      m_t = mnew;
      l_t *= alpha;
#pragma unroll
      for (int r2 = 0; r2 < 4; ++r2){
        float ar = __shfl(alpha, quad * 4 + r2, 64);
#pragma unroll
        for (int n = 0; n < 16; ++n) oacc[n][r2] *= ar;
      }
    }
    float rs = 0.f;
#pragma unroll
    for (int mb = 0; mb < 4; ++mb){
      float p0 = __expf(sacc[mb][0] - m_t);
      float p1 = __expf(sacc[mb][1] - m_t);
      float p2 = __expf(sacc[mb][2] - m_t);
      float p3 = __expf(sacc[mb][3] - m_t);
      rs += (p0 + p1) + (p2 + p3);
      unsigned int w0 = (unsigned)f2bf(p0) | ((unsigned)f2bf(p1) << 16);
      unsigned int w1 = (unsigned)f2bf(p2) | ((unsigned)f2bf(p3) << 16);
      // P[trow][s=mb*16+quad*4 .. +3] into wave-private region, 16B-granule XOR swizzle
      int pos = (2 * mb + (quad >> 1)) ^ swr;
      uint2 w; w.x = w0; w.y = w1;
      *(uint2*)&PW[l16 * 64 + pos * 8 + (quad & 1) * 4] = w;
    }
    rs += __shfl_xor(rs, 16, 64);
    rs += __shfl_xor(rs, 32, 64);
    l_t += rs;

    // O += P(A: m=t, wave-private) x ckvT(B: n=l)  — no barrier needed around P
    short8 a0 = *(const short8*)&PW[l16 * 64 + ((quad ^ swr) << 3)];
    short8 a1 = *(const short8*)&PW[l16 * 64 + (((4 + quad) ^ swr) << 3)];
    __builtin_amdgcn_s_setprio(1);
#pragma unroll
    for (int n = 0; n < 16; ++n){
      int lr_ = n * 16 + l16;
      int swl = lr_ & 7;
      short8 b0 = *(const short8*)&X1[lr_ * 64 + ((quad ^ swl) << 3)];
      short8 b1 = *(const short8*)&X1[lr_ * 64 + (((4 + quad) ^ swl) << 3)];
      oacc[n] = MFMA_BF16(a0, b0, oacc[n], 0, 0, 0);
      oacc[n] = MFMA_BF16(a1, b1, oacc[n], 0, 0, 0);
    }
    __builtin_amdgcn_s_setprio(0);
  }

  // ---- finalize: ctx = O / l -> park, y = ctx @ Vt
  __syncthreads();
  {
    float linv = 1.f / l_t;
#pragma unroll
    for (int r = 0; r < 4; ++r){
      float lr_ = __shfl(linv, quad * 4 + r, 64);
#pragma unroll
      for (int n = 0; n < 16; ++n) oacc[n][r] *= lr_;
    }
#pragma unroll
    for (int n = 0; n < 16; ++n)
#pragma unroll
      for (int r = 0; r < 4; ++r){
        int trw = wg * 16 + quad * 4 + r;
        int l = n * 16 + l16;
        int cs = (((l >> 3) ^ (trw & 7)) << 3) | (l & 7);
        LDS[trw * 256 + cs] = f2bf(oacc[n][r]);
      }
  }
  __syncthreads();
  {
    const u16* vth = Vt + (long)h * 64 * 256;
    short8 ca[8];
#pragma unroll
    for (int ks = 0; ks < 8; ++ks){
      int gl = ks * 4 + quad;
      ca[ks] = *(const short8*)&LDS[trow * 256 + ((gl ^ swr) << 3)];
    }
#pragma unroll
    for (int n = 0; n < 4; ++n){
      f32x4 acc = (f32x4){0.f, 0.f, 0.f, 0.f};
#pragma unroll
      for (int ks = 0; ks < 8; ++ks){
        short8 vb = *(const short8*)&vth[(n * 16 + l16) * 256 + ks * 32 + quad * 8];
        acc = MFMA_BF16(ca[ks], vb, acc, 0, 0, 0);
      }
#pragma unroll
      for (int r = 0; r < 4; ++r)
        y[(tglob + wg * 16 + quad * 4 + r) * 1024 + h * 64 + n * 16 + l16] = acc[r];
    }
  }
}

extern "C" void kernel_launch(void* const* d_in, const int* in_sizes, int n_in,
                              void* d_out, int out_size, void* d_ws, size_t ws_size,
                              hipStream_t stream)
{
  (void)in_sizes; (void)n_in; (void)out_size; (void)ws_size;
  const float* x    = (const float*)d_in[0];
  const float* Wdq  = (const float*)d_in[1];
  const float* Wuq  = (const float*)d_in[2];
  const float* Wdkv = (const float*)d_in[3];
  const float* Wuk  = (const float*)d_in[4];
  const float* Wuv  = (const float*)d_in[5];
  const float* Wo   = (const float*)d_in[6];

  float* y_out   = (float*)d_out;                      // (4,2048,1024) fp32
  float* ckv_out = y_out + (size_t)4 * 2048 * 1024;    // (4,2048,256) fp32

  char* base = (char*)d_ws;
  float* wdqT   = (float*)(base + 0);          // 1 MB, dead after keffT
  float* wuqT   = (float*)(base + 1048576);    // 1 MB, dead after pt
  float* wukT   = (float*)(base + 2097152);    // 1 MB, dead after t1T
  float* wuvT   = (float*)(base + 3145728);    // 1 MB, dead after vt
  u16*   ckvT   = (u16*)  (base + 0);          // 4 MB (4,256,2048) written after weights dead
  float* t1T    = (float*)(base + 4194304);    // 256 KB
  float* keffT  = (float*)(base + 4456448);    // 1 MB
  u16*   pt     = (u16*)  (base + 5505024);    // 2 MB (16,256,256), 1/8 folded
  u16*   vt     = (u16*)  (base + 7602176);    // 512 KB (1024,256)
  u16*   xq     = (u16*)  (base + 8126464);    // 4 MB (8192,256)
  u16*   ckv_bf = (u16*)  (base + 12320768);   // 4 MB (4,2048,256) bf16

  k_transpose4<<<dim3(32, 32, 4), dim3(32, 8), 0, stream>>>(
      Wdq, wdqT, Wuq, wuqT, Wuk, wukT, Wuv, wuvT);

  k_gemm_nt<<<dim3(4, 4, 1), 256, 0, stream>>>(wukT, wuqT, t1T, (u16*)0,
      256, 256, 1024, 1024, 1024, 256, 0, 0, 0, 1.f);
  k_gemm_nt<<<dim3(16, 4, 1), 256, 0, stream>>>(t1T, wdqT, keffT, (u16*)0,
      256, 1024, 256, 256, 256, 1024, 0, 0, 0, 1.f);
  k_gemm_nt<<<dim3(4, 4, 16), 256, 0, stream>>>(keffT, wuqT, (float*)0, pt,
      256, 256, 64, 1024, 1024, 256, 64, 64, 65536, 0.125f);
  k_gemm_nt<<<dim3(4, 16, 1), 256, 0, stream>>>(Wo, wuvT, (float*)0, vt,
      1024, 256, 1024, 1024, 1024, 256, 0, 0, 0, 1.f);

  // fused: xq (bf16), ckv (fp32 -> d_out, bf16, bf16-transposed)
  k_proj2<<<dim3(256), 512, 0, stream>>>(x, Wdq, Wdkv, xq, ckv_out, ckv_bf, ckvT);

  k_flash<<<dim3(16, 16, 4), 512, 0, stream>>>(xq, pt, ckv_bf, ckvT, vt, y_out);
}

// Round 13
// 622.407 us; speedup vs baseline: 1.1699x; 1.1699x over previous
//
#include <hip/hip_runtime.h>

typedef unsigned short u16;
typedef __attribute__((ext_vector_type(8))) short short8;
typedef __attribute__((ext_vector_type(4))) float f32x4;

#define MFMA_BF16 __builtin_amdgcn_mfma_f32_16x16x32_bf16

// ckvT chunk table (u16 units): b3 relocated to the dead keffT region because
// wuvT (bytes 3M..4M) stays alive through the merged proj+vt kernel.
// {0, wuqT, wukT, keffT} regions — all dead writers/readers by merge time.
#define CKVT_OFF(b) ((b)==0 ? 0L : (b)==1 ? 524288L : (b)==2 ? 1048576L : 2228224L)

__device__ __forceinline__ u16 f2bf(float f){
  unsigned int u = __builtin_bit_cast(unsigned int, f);
  u += 0x7fffu + ((u >> 16) & 1u);
  return (u16)(u >> 16);
}

// async global->LDS 16B: lane i writes lds_base + i*16
__device__ __forceinline__ void gld16(const void* g, void* l){
  __builtin_amdgcn_global_load_lds(
      (const __attribute__((address_space(1))) unsigned int*)g,
      (__attribute__((address_space(3))) unsigned int*)l, 16, 0, 0);
}

// ---------------- batched fp32 transposes of the 4 weights ----------------
// z=0: Wdq (256x1024)->wdqT ; z=1..3: Wuq/Wuk/Wuv (1024x256)->T
__global__ void k_transpose4(const float* __restrict__ s0, float* __restrict__ d0,
                             const float* __restrict__ s1, float* __restrict__ d1,
                             const float* __restrict__ s2, float* __restrict__ d2,
                             const float* __restrict__ s3, float* __restrict__ d3)
{
  __shared__ float tile[32][33];
  int z = blockIdx.z;
  const float* src = z == 0 ? s0 : z == 1 ? s1 : z == 2 ? s2 : s3;
  float* dst       = z == 0 ? d0 : z == 1 ? d1 : z == 2 ? d2 : d3;
  int rows = z == 0 ? 256 : 1024, cols = z == 0 ? 1024 : 256;
  int c0 = blockIdx.x * 32, r0 = blockIdx.y * 32;
  if (c0 >= cols || r0 >= rows) return;
  int tx = threadIdx.x, ty = threadIdx.y;
#pragma unroll
  for (int i = 0; i < 4; ++i){
    int r = ty + i * 8;
    tile[r][tx] = src[(long)(r0 + r) * cols + c0 + tx];
  }
  __syncthreads();
#pragma unroll
  for (int i = 0; i < 4; ++i){
    int r = ty + i * 8;
    dst[(long)(c0 + r) * rows + r0 + tx] = tile[tx][r];
  }
}

// ---------------- NT MFMA GEMM: C[M,N] = scale * A[M,K] * B[N,K]^T ----------------
__global__ __launch_bounds__(256)
void k_gemm_nt(const float* __restrict__ A, const float* __restrict__ B,
               float* __restrict__ Cf, u16* __restrict__ Cb,
               int M, int N, int K, int lda, int ldb, int ldc,
               long sA, long sB, long sC, float scale)
{
  A += (long)blockIdx.z * sA; B += (long)blockIdx.z * sB;
  if (Cf) Cf += (long)blockIdx.z * sC;
  if (Cb) Cb += (long)blockIdx.z * sC;
  const int n0 = blockIdx.x * 64, m0 = blockIdx.y * 64;
  const int tid = threadIdx.x;
  const int wave = tid >> 6, lane = tid & 63, quad = lane >> 4, l16 = lane & 15;
  __shared__ u16 As[64 * 40];
  __shared__ u16 Bs[64 * 40];
  f32x4 acc[4];
#pragma unroll
  for (int n = 0; n < 4; ++n) acc[n] = (f32x4){0.f, 0.f, 0.f, 0.f};

  const int lr = tid >> 2;
  const int lc = (tid & 3) * 8;
  for (int k0 = 0; k0 < K; k0 += 32){
    {
      const float* pa = &A[(long)(m0 + lr) * lda + k0 + lc];
      float4 a0 = *(const float4*)pa;
      float4 a1 = *(const float4*)(pa + 4);
      short8 pk;
      pk[0]=(short)f2bf(a0.x); pk[1]=(short)f2bf(a0.y); pk[2]=(short)f2bf(a0.z); pk[3]=(short)f2bf(a0.w);
      pk[4]=(short)f2bf(a1.x); pk[5]=(short)f2bf(a1.y); pk[6]=(short)f2bf(a1.z); pk[7]=(short)f2bf(a1.w);
      *(short8*)&As[lr * 40 + lc] = pk;
      const float* pb = &B[(long)(n0 + lr) * ldb + k0 + lc];
      float4 b0 = *(const float4*)pb;
      float4 b1 = *(const float4*)(pb + 4);
      short8 qk;
      qk[0]=(short)f2bf(b0.x); qk[1]=(short)f2bf(b0.y); qk[2]=(short)f2bf(b0.z); qk[3]=(short)f2bf(b0.w);
      qk[4]=(short)f2bf(b1.x); qk[5]=(short)f2bf(b1.y); qk[6]=(short)f2bf(b1.z); qk[7]=(short)f2bf(b1.w);
      *(short8*)&Bs[lr * 40 + lc] = qk;
    }
    __syncthreads();
    short8 a = *(const short8*)&As[(wave * 16 + l16) * 40 + quad * 8];
#pragma unroll
    for (int n = 0; n < 4; ++n){
      short8 b = *(const short8*)&Bs[(n * 16 + l16) * 40 + quad * 8];
      acc[n] = MFMA_BF16(a, b, acc[n], 0, 0, 0);
    }
    __syncthreads();
  }
#pragma unroll
  for (int n = 0; n < 4; ++n)
#pragma unroll
    for (int r = 0; r < 4; ++r){
      int row = m0 + wave * 16 + quad * 4 + r;
      int col = n0 + n * 16 + l16;
      float v = acc[n][r] * scale;
      if (Cf) Cf[(long)row * ldc + col] = v;
      if (Cb) Cb[(long)row * ldc + col] = f2bf(v);
    }
}

// ---------------- split-K GEMM for t1T (round 13) ----------------
// t1T[256,256] += wukT[256, z*128..+128] @ wuqT[.,same]^T, atomicAdd epilogue.
// Old g1 ran 16 blocks on 256 CUs (latency-bound, ~30us); split-K x8 -> 128
// blocks x 4 k-iters (~10us). t1T zeroed via hipMemsetAsync (graph-safe).
__global__ __launch_bounds__(256)
void k_gemm_sk(const float* __restrict__ A, const float* __restrict__ B,
               float* __restrict__ Cf)
{
  const int n0 = blockIdx.x * 64, m0 = blockIdx.y * 64;
  const int kbase = blockIdx.z * 128;
  const int tid = threadIdx.x;
  const int wave = tid >> 6, lane = tid & 63, quad = lane >> 4, l16 = lane & 15;
  __shared__ u16 As[64 * 40];
  __shared__ u16 Bs[64 * 40];
  f32x4 acc[4];
#pragma unroll
  for (int n = 0; n < 4; ++n) acc[n] = (f32x4){0.f, 0.f, 0.f, 0.f};

  const int lr = tid >> 2;
  const int lc = (tid & 3) * 8;
  for (int k0 = kbase; k0 < kbase + 128; k0 += 32){
    {
      const float* pa = &A[(long)(m0 + lr) * 1024 + k0 + lc];
      float4 a0 = *(const float4*)pa;
      float4 a1 = *(const float4*)(pa + 4);
      short8 pk;
      pk[0]=(short)f2bf(a0.x); pk[1]=(short)f2bf(a0.y); pk[2]=(short)f2bf(a0.z); pk[3]=(short)f2bf(a0.w);
      pk[4]=(short)f2bf(a1.x); pk[5]=(short)f2bf(a1.y); pk[6]=(short)f2bf(a1.z); pk[7]=(short)f2bf(a1.w);
      *(short8*)&As[lr * 40 + lc] = pk;
      const float* pb = &B[(long)(n0 + lr) * 1024 + k0 + lc];
      float4 b0 = *(const float4*)pb;
      float4 b1 = *(const float4*)(pb + 4);
      short8 qk;
      qk[0]=(short)f2bf(b0.x); qk[1]=(short)f2bf(b0.y); qk[2]=(short)f2bf(b0.z); qk[3]=(short)f2bf(b0.w);
      qk[4]=(short)f2bf(b1.x); qk[5]=(short)f2bf(b1.y); qk[6]=(short)f2bf(b1.z); qk[7]=(short)f2bf(b1.w);
      *(short8*)&Bs[lr * 40 + lc] = qk;
    }
    __syncthreads();
    short8 a = *(const short8*)&As[(wave * 16 + l16) * 40 + quad * 8];
#pragma unroll
    for (int n = 0; n < 4; ++n){
      short8 b = *(const short8*)&Bs[(n * 16 + l16) * 40 + quad * 8];
      acc[n] = MFMA_BF16(a, b, acc[n], 0, 0, 0);
    }
    __syncthreads();
  }
#pragma unroll
  for (int n = 0; n < 4; ++n)
#pragma unroll
    for (int r = 0; r < 4; ++r){
      int row = m0 + wave * 16 + quad * 4 + r;
      int col = n0 + n * 16 + l16;
      atomicAdd(&Cf[(long)row * 256 + col], acc[n][r]);
    }
}

// ---------------- merged projections + vt GEMM (round 13) ----------------
// y<128: old k_proj body (proven; r12 showed k_proj2 was not better) with
// chunked ckvT. y>=128: 64 blocks computing vt = Wo @ wuvT^T (old g4) — rides
// the proj launch's tail round ~free, saving a serial ~30us launch.
__global__ __launch_bounds__(256)
void k_projv(const float* __restrict__ x, const float* __restrict__ Wdq,
             const float* __restrict__ Wdkv, u16* __restrict__ xq,
             float* __restrict__ ckv_f, u16* __restrict__ ckv_bf, u16* __restrict__ ckvT,
             const float* __restrict__ Wo, const float* __restrict__ wuvT,
             u16* __restrict__ vt)
{
  const int tid = threadIdx.x;
  const int wave = tid >> 6, lane = tid & 63, quad = lane >> 4, l16 = lane & 15;
  __shared__ u16 As[64 * 40];
  __shared__ u16 Bs[64 * 40];
  f32x4 acc[4];
#pragma unroll
  for (int n = 0; n < 4; ++n) acc[n] = (f32x4){0.f, 0.f, 0.f, 0.f};
  const int lr = tid >> 2;
  const int lc = (tid & 3) * 8;

  if (blockIdx.y >= 128){
    // ---- vt block: vt[1024,256] = bf16(Wo @ wuvT^T), tile t
    const int t = (blockIdx.y - 128) * 8 + blockIdx.x;   // 0..63
    const int m0 = (t >> 2) * 64, n0 = (t & 3) * 64;
    for (int k0 = 0; k0 < 1024; k0 += 32){
      {
        const float* pa = &Wo[(long)(m0 + lr) * 1024 + k0 + lc];
        float4 a0 = *(const float4*)pa;
        float4 a1 = *(const float4*)(pa + 4);
        short8 pk;
        pk[0]=(short)f2bf(a0.x); pk[1]=(short)f2bf(a0.y); pk[2]=(short)f2bf(a0.z); pk[3]=(short)f2bf(a0.w);
        pk[4]=(short)f2bf(a1.x); pk[5]=(short)f2bf(a1.y); pk[6]=(short)f2bf(a1.z); pk[7]=(short)f2bf(a1.w);
        *(short8*)&As[lr * 40 + lc] = pk;
        const float* pb = &wuvT[(long)(n0 + lr) * 1024 + k0 + lc];
        float4 b0 = *(const float4*)pb;
        float4 b1 = *(const float4*)(pb + 4);
        short8 qk;
        qk[0]=(short)f2bf(b0.x); qk[1]=(short)f2bf(b0.y); qk[2]=(short)f2bf(b0.z); qk[3]=(short)f2bf(b0.w);
        qk[4]=(short)f2bf(b1.x); qk[5]=(short)f2bf(b1.y); qk[6]=(short)f2bf(b1.z); qk[7]=(short)f2bf(b1.w);
        *(short8*)&Bs[lr * 40 + lc] = qk;
      }
      __syncthreads();
      short8 a = *(const short8*)&As[(wave * 16 + l16) * 40 + quad * 8];
#pragma unroll
      for (int n = 0; n < 4; ++n){
        short8 b = *(const short8*)&Bs[(n * 16 + l16) * 40 + quad * 8];
        acc[n] = MFMA_BF16(a, b, acc[n], 0, 0, 0);
      }
      __syncthreads();
    }
#pragma unroll
    for (int n = 0; n < 4; ++n)
#pragma unroll
      for (int r = 0; r < 4; ++r){
        int row = m0 + wave * 16 + quad * 4 + r;
        int col = n0 + n * 16 + l16;
        vt[(long)row * 256 + col] = f2bf(acc[n][r]);
      }
    return;
  }

  // ---- proj block (old k_proj body, chunked ckvT)
  const bool is_kv = blockIdx.x >= 4;
  const float* B = is_kv ? Wdkv : Wdq;
  const int n0 = (blockIdx.x & 3) * 64, m0 = blockIdx.y * 64;
  for (int k0 = 0; k0 < 1024; k0 += 32){
    {
      const float* pa = &x[(long)(m0 + lr) * 1024 + k0 + lc];
      float4 a0 = *(const float4*)pa;
      float4 a1 = *(const float4*)(pa + 4);
      short8 pk;
      pk[0]=(short)f2bf(a0.x); pk[1]=(short)f2bf(a0.y); pk[2]=(short)f2bf(a0.z); pk[3]=(short)f2bf(a0.w);
      pk[4]=(short)f2bf(a1.x); pk[5]=(short)f2bf(a1.y); pk[6]=(short)f2bf(a1.z); pk[7]=(short)f2bf(a1.w);
      *(short8*)&As[lr * 40 + lc] = pk;
      const float* pb = &B[(long)(n0 + lr) * 1024 + k0 + lc];
      float4 b0 = *(const float4*)pb;
      float4 b1 = *(const float4*)(pb + 4);
      short8 qk;
      qk[0]=(short)f2bf(b0.x); qk[1]=(short)f2bf(b0.y); qk[2]=(short)f2bf(b0.z); qk[3]=(short)f2bf(b0.w);
      qk[4]=(short)f2bf(b1.x); qk[5]=(short)f2bf(b1.y); qk[6]=(short)f2bf(b1.z); qk[7]=(short)f2bf(b1.w);
      *(short8*)&Bs[lr * 40 + lc] = qk;
    }
    __syncthreads();
    short8 a = *(const short8*)&As[(wave * 16 + l16) * 40 + quad * 8];
#pragma unroll
    for (int n = 0; n < 4; ++n){
      short8 b = *(const short8*)&Bs[(n * 16 + l16) * 40 + quad * 8];
      acc[n] = MFMA_BF16(a, b, acc[n], 0, 0, 0);
    }
    __syncthreads();
  }
  if (!is_kv){
#pragma unroll
    for (int n = 0; n < 4; ++n)
#pragma unroll
      for (int r = 0; r < 4; ++r){
        int row = m0 + wave * 16 + quad * 4 + r;
        int col = n0 + n * 16 + l16;
        xq[(long)row * 256 + col] = f2bf(acc[n][r]);
      }
  } else {
    const int bb = (m0 >> 11);
    const long cbase = CKVT_OFF(bb);
    const int t0 = (m0 & 2047) + wave * 16 + quad * 4;
#pragma unroll
    for (int n = 0; n < 4; ++n){
      int col = n0 + n * 16 + l16;
      u16 pk[4];
#pragma unroll
      for (int r = 0; r < 4; ++r){
        int row = m0 + wave * 16 + quad * 4 + r;
        float v = acc[n][r];
        ckv_f [(long)row * 256 + col] = v;
        ckv_bf[(long)row * 256 + col] = f2bf(v);
        pk[r] = f2bf(v);
      }
      *(uint2*)&ckvT[cbase + (long)col * 2048 + t0] = *(uint2*)pk;
    }
  }
}

// ---------------- fused MLA flash attention ----------------
// Round-7 version (best: 486us) with chunked-ckvT base lookup. QT=128,
// KVBLK=64, dbuf, 1 barrier/iter, XCD-balanced qt pairing. Register wall
// (r4/r5/r8/r10): 2 waves/SIMD spill-free is this design's optimum.
__global__ __launch_bounds__(512, 2)
void k_flash(const u16* __restrict__ xq, const u16* __restrict__ Pt,
             const u16* __restrict__ ckv_bf, const u16* __restrict__ ckvT,
             const u16* __restrict__ Vt, float* __restrict__ y)
{
  const int bx = blockIdx.x;
  const int qt = (bx < 8) ? (15 - bx) : (bx - 8);   // XCD-balanced pairing
  const int h = blockIdx.y, b = blockIdx.z;
  const int tid = threadIdx.x;
  const int wg = tid >> 6, lane = tid & 63, quad = lane >> 4, l16 = lane & 15;

  __shared__ u16 LDS[73728];
  u16* PW = LDS + 65536 + wg * 1024;

  const int trow = wg * 16 + l16;
  const int swr  = l16 & 7;
  const long tglob = (long)b * 2048 + qt * 128;

  const u16* ckv_b  = ckv_bf + (long)b * 2048 * 256;
  const u16* ckvT_b = ckvT + CKVT_OFF(b);

  int offA[4], offB[4];
  {
    int l5 = lane >> 5, g32 = lane & 31;
#pragma unroll
    for (int j = 0; j < 4; ++j){
      int s = (wg * 4 + j) * 2 + l5;
      offA[j] = s * 256 + ((g32 ^ (s & 7)) * 8);
    }
    int l3 = lane >> 3, g8 = lane & 7;
#pragma unroll
    for (int j = 0; j < 4; ++j){
      int l = (wg * 4 + j) * 8 + l3;
      offB[j] = l * 2048 + ((g8 ^ (l & 7)) * 8);
    }
  }

  // ---- phase 0: q_lat^T = Pt[h](A) x xq(B); park in LDS[0..32768), read back aS
  short8 aS[8];
  {
    short8 bq[8];
    const u16* xr = xq + (tglob + trow) * 256;
#pragma unroll
    for (int ks = 0; ks < 8; ++ks)
      bq[ks] = *(const short8*)&xr[ks * 32 + quad * 8];
    const u16* pth = Pt + (long)h * 65536;
#pragma unroll
    for (int mb = 0; mb < 16; ++mb){
      f32x4 acc = (f32x4){0.f, 0.f, 0.f, 0.f};
#pragma unroll
      for (int ks = 0; ks < 8; ++ks){
        short8 pa = *(const short8*)&pth[(mb * 16 + l16) * 256 + ks * 32 + quad * 8];
        acc = MFMA_BF16(pa, bq[ks], acc, 0, 0, 0);
      }
#pragma unroll
      for (int r = 0; r < 4; ++r){
        int l = mb * 16 + quad * 4 + r;
        int cs = (((l >> 3) ^ swr) << 3) | (l & 7);
        LDS[trow * 256 + cs] = f2bf(acc[r]);
      }
    }
  }
  __syncthreads();
#pragma unroll
  for (int ks = 0; ks < 8; ++ks){
    int gl = ks * 4 + quad;
    aS[ks] = *(const short8*)&LDS[trow * 256 + ((gl ^ swr) << 3)];
  }
  __syncthreads();

  // prologue: stage tile 0 into buffer 0
#pragma unroll
  for (int j = 0; j < 4; ++j)
    gld16(ckv_b + offA[j], &LDS[(wg * 4 + j) * 512]);
#pragma unroll
  for (int j = 0; j < 4; ++j)
    gld16(ckvT_b + offB[j], &LDS[32768 + (wg * 4 + j) * 512]);

  // ---- phase 1: online-softmax KV loop (double-buffered, 1 barrier/iter)
  float m_t = -1e30f, l_t = 0.f;
  f32x4 oacc[16];
#pragma unroll
  for (int n = 0; n < 16; ++n) oacc[n] = (f32x4){0.f, 0.f, 0.f, 0.f};

  const int stmax = 2 * qt + 1;
  const int tg = qt * 128 + trow;
  for (int st = 0; st <= stmax; ++st){
    const int cur = st & 1;
    __syncthreads();
    if (st < stmax){
      const int nx = cur ^ 1;
#pragma unroll
      for (int j = 0; j < 4; ++j)
        gld16(ckv_b + (long)(st + 1) * 16384 + offA[j],
              &LDS[nx * 16384 + (wg * 4 + j) * 512]);
#pragma unroll
      for (int j = 0; j < 4; ++j)
        gld16(ckvT_b + (st + 1) * 64 + offB[j],
              &LDS[32768 + nx * 16384 + (wg * 4 + j) * 512]);
    }
    if (st * 64 > qt * 128 + wg * 16 + 15) continue;

    const u16* X0 = LDS + cur * 16384;
    const u16* X1 = LDS + 32768 + cur * 16384;

    f32x4 sacc[4];
#pragma unroll
    for (int mb = 0; mb < 4; ++mb) sacc[mb] = (f32x4){0.f, 0.f, 0.f, 0.f};
    __builtin_amdgcn_s_setprio(1);
#pragma unroll
    for (int ks = 0; ks < 8; ++ks){
      int gl = ks * 4 + quad;
#pragma unroll
      for (int mb = 0; mb < 4; ++mb){
        short8 a = *(const short8*)&X0[(mb * 16 + l16) * 256 + ((gl ^ swr) << 3)];
        sacc[mb] = MFMA_BF16(a, aS[ks], sacc[mb], 0, 0, 0);
      }
    }
    __builtin_amdgcn_s_setprio(0);

    if (st * 64 + 63 > tg){
#pragma unroll
      for (int mb = 0; mb < 4; ++mb)
#pragma unroll
        for (int r = 0; r < 4; ++r)
          if (st * 64 + mb * 16 + quad * 4 + r > tg) sacc[mb][r] = -1e30f;
    }

    float rm = sacc[0][0];
#pragma unroll
    for (int mb = 0; mb < 4; ++mb)
#pragma unroll
      for (int r = 0; r < 4; ++r) rm = fmaxf(rm, sacc[mb][r]);
    rm = fmaxf(rm, __shfl_xor(rm, 16, 64));
    rm = fmaxf(rm, __shfl_xor(rm, 32, 64));
    if (!__all(rm <= m_t + 8.f)){
      float mnew = fmaxf(m_t, rm);
      float alpha = __expf(m_t - mnew);
      m_t = mnew;
      l_t *= alpha;
#pragma unroll
      for (int r2 = 0; r2 < 4; ++r2){
        float ar = __shfl(alpha, quad * 4 + r2, 64);
#pragma unroll
        for (int n = 0; n < 16; ++n) oacc[n][r2] *= ar;
      }
    }
    float rs = 0.f;
#pragma unroll
    for (int mb = 0; mb < 4; ++mb){
      float p0 = __expf(sacc[mb][0] - m_t);
      float p1 = __expf(sacc[mb][1] - m_t);
      float p2 = __expf(sacc[mb][2] - m_t);
      float p3 = __expf(sacc[mb][3] - m_t);
      rs += (p0 + p1) + (p2 + p3);
      unsigned int w0 = (unsigned)f2bf(p0) | ((unsigned)f2bf(p1) << 16);
      unsigned int w1 = (unsigned)f2bf(p2) | ((unsigned)f2bf(p3) << 16);
      int pos = (2 * mb + (quad >> 1)) ^ swr;
      uint2 w; w.x = w0; w.y = w1;
      *(uint2*)&PW[l16 * 64 + pos * 8 + (quad & 1) * 4] = w;
    }
    rs += __shfl_xor(rs, 16, 64);
    rs += __shfl_xor(rs, 32, 64);
    l_t += rs;

    short8 a0 = *(const short8*)&PW[l16 * 64 + ((quad ^ swr) << 3)];
    short8 a1 = *(const short8*)&PW[l16 * 64 + (((4 + quad) ^ swr) << 3)];
    __builtin_amdgcn_s_setprio(1);
#pragma unroll
    for (int n = 0; n < 16; ++n){
      int lr_ = n * 16 + l16;
      int swl = lr_ & 7;
      short8 b0 = *(const short8*)&X1[lr_ * 64 + ((quad ^ swl) << 3)];
      short8 b1 = *(const short8*)&X1[lr_ * 64 + (((4 + quad) ^ swl) << 3)];
      oacc[n] = MFMA_BF16(a0, b0, oacc[n], 0, 0, 0);
      oacc[n] = MFMA_BF16(a1, b1, oacc[n], 0, 0, 0);
    }
    __builtin_amdgcn_s_setprio(0);
  }

  // ---- finalize: ctx = O / l -> park, y = ctx @ Vt
  __syncthreads();
  {
    float linv = 1.f / l_t;
#pragma unroll
    for (int r = 0; r < 4; ++r){
      float lr_ = __shfl(linv, quad * 4 + r, 64);
#pragma unroll
      for (int n = 0; n < 16; ++n) oacc[n][r] *= lr_;
    }
#pragma unroll
    for (int n = 0; n < 16; ++n)
#pragma unroll
      for (int r = 0; r < 4; ++r){
        int trw = wg * 16 + quad * 4 + r;
        int l = n * 16 + l16;
        int cs = (((l >> 3) ^ (trw & 7)) << 3) | (l & 7);
        LDS[trw * 256 + cs] = f2bf(oacc[n][r]);
      }
  }
  __syncthreads();
  {
    const u16* vth = Vt + (long)h * 64 * 256;
    short8 ca[8];
#pragma unroll
    for (int ks = 0; ks < 8; ++ks){
      int gl = ks * 4 + quad;
      ca[ks] = *(const short8*)&LDS[trow * 256 + ((gl ^ swr) << 3)];
    }
#pragma unroll
    for (int n = 0; n < 4; ++n){
      f32x4 acc = (f32x4){0.f, 0.f, 0.f, 0.f};
#pragma unroll
      for (int ks = 0; ks < 8; ++ks){
        short8 vb = *(const short8*)&vth[(n * 16 + l16) * 256 + ks * 32 + quad * 8];
        acc = MFMA_BF16(ca[ks], vb, acc, 0, 0, 0);
      }
#pragma unroll
      for (int r = 0; r < 4; ++r)
        y[(tglob + wg * 16 + quad * 4 + r) * 1024 + h * 64 + n * 16 + l16] = acc[r];
    }
  }
}

extern "C" void kernel_launch(void* const* d_in, const int* in_sizes, int n_in,
                              void* d_out, int out_size, void* d_ws, size_t ws_size,
                              hipStream_t stream)
{
  (void)in_sizes; (void)n_in; (void)out_size; (void)ws_size;
  const float* x    = (const float*)d_in[0];
  const float* Wdq  = (const float*)d_in[1];
  const float* Wuq  = (const float*)d_in[2];
  const float* Wdkv = (const float*)d_in[3];
  const float* Wuk  = (const float*)d_in[4];
  const float* Wuv  = (const float*)d_in[5];
  const float* Wo   = (const float*)d_in[6];

  float* y_out   = (float*)d_out;                      // (4,2048,1024) fp32
  float* ckv_out = y_out + (size_t)4 * 2048 * 1024;    // (4,2048,256) fp32

  char* base = (char*)d_ws;
  float* wdqT   = (float*)(base + 0);          // 1 MB, dead after keffT (g2)
  float* wuqT   = (float*)(base + 1048576);    // 1 MB, dead after pt (g3)
  float* wukT   = (float*)(base + 2097152);    // 1 MB, dead after t1T (g1)
  float* wuvT   = (float*)(base + 3145728);    // 1 MB, read by vt blocks in k_projv
  u16*   ckvT   = (u16*)  (base + 0);          // chunked: b0@0 b1@1M b2@2M b3@keffT
  float* t1T    = (float*)(base + 4194304);    // 256 KB
  float* keffT  = (float*)(base + 4456448);    // 1 MB, dead after g3 -> ckvT b3
  u16*   pt     = (u16*)  (base + 5505024);    // 2 MB (16,256,256)
  u16*   vt     = (u16*)  (base + 7602176);    // 512 KB (1024,256)
  u16*   xq     = (u16*)  (base + 8126464);    // 4 MB (8192,256)
  u16*   ckv_bf = (u16*)  (base + 12320768);   // 4 MB (4,2048,256) bf16

  // zero t1T for split-K atomic accumulation (graph-capture-safe)
  hipMemsetAsync(t1T, 0, 256 * 256 * sizeof(float), stream);

  k_transpose4<<<dim3(32, 32, 4), dim3(32, 8), 0, stream>>>(
      Wdq, wdqT, Wuq, wuqT, Wuk, wukT, Wuv, wuvT);

  // g1 split-K x8: t1T += wukT @ wuqT^T
  k_gemm_sk<<<dim3(4, 4, 8), 256, 0, stream>>>(wukT, wuqT, t1T);

  k_gemm_nt<<<dim3(16, 4, 1), 256, 0, stream>>>(t1T, wdqT, keffT, (u16*)0,
      256, 1024, 256, 256, 256, 1024, 0, 0, 0, 1.f);
  k_gemm_nt<<<dim3(4, 4, 16), 256, 0, stream>>>(keffT, wuqT, (float*)0, pt,
      256, 256, 64, 1024, 1024, 256, 64, 64, 65536, 0.125f);

  // merged: proj (xq, ckv fp32/bf16/bf16-T chunked) + vt = Wo @ wuvT^T
  k_projv<<<dim3(8, 136), 256, 0, stream>>>(x, Wdq, Wdkv, xq, ckv_out, ckv_bf,
                                            ckvT, Wo, wuvT, vt);

  k_flash<<<dim3(16, 16, 4), 512, 0, stream>>>(xq, pt, ckv_bf, ckvT, vt, y_out);
}

// Round 15
// 617.628 us; speedup vs baseline: 1.1789x; 1.0077x over previous
//
#include <hip/hip_runtime.h>

typedef unsigned short u16;
typedef __attribute__((ext_vector_type(8))) short short8;
typedef __attribute__((ext_vector_type(4))) float f32x4;
typedef __attribute__((ext_vector_type(4))) unsigned int u32x4;

#define MFMA_BF16 __builtin_amdgcn_mfma_f32_16x16x32_bf16

// ckvT chunk table (u16 units): b3 relocated to the dead keffT region because
// wuvT (bytes 3M..4M) stays alive through the merged proj+vt kernel (r13).
#define CKVT_OFF(b) ((b)==0 ? 0L : (b)==1 ? 524288L : (b)==2 ? 1048576L : 2228224L)

__device__ __forceinline__ u16 f2bf(float f){
  unsigned int u = __builtin_bit_cast(unsigned int, f);
  u += 0x7fffu + ((u >> 16) & 1u);
  return (u16)(u >> 16);
}

// r15: packed RNE fp32->bf16 via v_cvt_pk_bf16_f32 (1 op / 2 floats).
// Bit-identical to f2bf (both RNE); cuts staging-conversion VALU ~8x —
// the r13 profile implies k_projv is conversion-VALU-bound (~6:1 VALU:MFMA).
__device__ __forceinline__ short8 pack8(float4 a0, float4 a1){
  unsigned p0, p1, p2, p3;
  asm("v_cvt_pk_bf16_f32 %0, %1, %2" : "=v"(p0) : "v"(a0.x), "v"(a0.y));
  asm("v_cvt_pk_bf16_f32 %0, %1, %2" : "=v"(p1) : "v"(a0.z), "v"(a0.w));
  asm("v_cvt_pk_bf16_f32 %0, %1, %2" : "=v"(p2) : "v"(a1.x), "v"(a1.y));
  asm("v_cvt_pk_bf16_f32 %0, %1, %2" : "=v"(p3) : "v"(a1.z), "v"(a1.w));
  u32x4 v; v.x = p0; v.y = p1; v.z = p2; v.w = p3;
  return __builtin_bit_cast(short8, v);
}

// async global->LDS 16B: lane i writes lds_base + i*16
__device__ __forceinline__ void gld16(const void* g, void* l){
  __builtin_amdgcn_global_load_lds(
      (const __attribute__((address_space(1))) unsigned int*)g,
      (__attribute__((address_space(3))) unsigned int*)l, 16, 0, 0);
}

// ---------------- batched fp32 transposes of the 4 weights ----------------
// z=0: Wdq (256x1024)->wdqT ; z=1..3: Wuq/Wuk/Wuv (1024x256)->T
// r15: z==0 blocks also zero t1T (64 floats each, before early-return) —
// replaces the hipMemsetAsync slot.
__global__ void k_transpose4(const float* __restrict__ s0, float* __restrict__ d0,
                             const float* __restrict__ s1, float* __restrict__ d1,
                             const float* __restrict__ s2, float* __restrict__ d2,
                             const float* __restrict__ s3, float* __restrict__ d3,
                             float* __restrict__ t1T)
{
  __shared__ float tile[32][33];
  int z = blockIdx.z;
  int tx = threadIdx.x, ty = threadIdx.y;
  if (z == 0){
    int bidl = blockIdx.y * 32 + blockIdx.x;   // 0..1023
    int t = ty * 32 + tx;                      // 0..255
    if (t < 64) t1T[bidl * 64 + t] = 0.f;      // 1024*64 = 65536 = full t1T
  }
  const float* src = z == 0 ? s0 : z == 1 ? s1 : z == 2 ? s2 : s3;
  float* dst       = z == 0 ? d0 : z == 1 ? d1 : z == 2 ? d2 : d3;
  int rows = z == 0 ? 256 : 1024, cols = z == 0 ? 1024 : 256;
  int c0 = blockIdx.x * 32, r0 = blockIdx.y * 32;
  if (c0 >= cols || r0 >= rows) return;
#pragma unroll
  for (int i = 0; i < 4; ++i){
    int r = ty + i * 8;
    tile[r][tx] = src[(long)(r0 + r) * cols + c0 + tx];
  }
  __syncthreads();
#pragma unroll
  for (int i = 0; i < 4; ++i){
    int r = ty + i * 8;
    dst[(long)(c0 + r) * rows + r0 + tx] = tile[tx][r];
  }
}

// ---------------- NT MFMA GEMM: C[M,N] = scale * A[M,K] * B[N,K]^T ----------------
__global__ __launch_bounds__(256)
void k_gemm_nt(const float* __restrict__ A, const float* __restrict__ B,
               float* __restrict__ Cf, u16* __restrict__ Cb,
               int M, int N, int K, int lda, int ldb, int ldc,
               long sA, long sB, long sC, float scale)
{
  A += (long)blockIdx.z * sA; B += (long)blockIdx.z * sB;
  if (Cf) Cf += (long)blockIdx.z * sC;
  if (Cb) Cb += (long)blockIdx.z * sC;
  const int n0 = blockIdx.x * 64, m0 = blockIdx.y * 64;
  const int tid = threadIdx.x;
  const int wave = tid >> 6, lane = tid & 63, quad = lane >> 4, l16 = lane & 15;
  __shared__ u16 As[64 * 40];
  __shared__ u16 Bs[64 * 40];
  f32x4 acc[4];
#pragma unroll
  for (int n = 0; n < 4; ++n) acc[n] = (f32x4){0.f, 0.f, 0.f, 0.f};

  const int lr = tid >> 2;
  const int lc = (tid & 3) * 8;
  for (int k0 = 0; k0 < K; k0 += 32){
    {
      const float* pa = &A[(long)(m0 + lr) * lda + k0 + lc];
      *(short8*)&As[lr * 40 + lc] = pack8(*(const float4*)pa, *(const float4*)(pa + 4));
      const float* pb = &B[(long)(n0 + lr) * ldb + k0 + lc];
      *(short8*)&Bs[lr * 40 + lc] = pack8(*(const float4*)pb, *(const float4*)(pb + 4));
    }
    __syncthreads();
    short8 a = *(const short8*)&As[(wave * 16 + l16) * 40 + quad * 8];
#pragma unroll
    for (int n = 0; n < 4; ++n){
      short8 b = *(const short8*)&Bs[(n * 16 + l16) * 40 + quad * 8];
      acc[n] = MFMA_BF16(a, b, acc[n], 0, 0, 0);
    }
    __syncthreads();
  }
#pragma unroll
  for (int n = 0; n < 4; ++n)
#pragma unroll
    for (int r = 0; r < 4; ++r){
      int row = m0 + wave * 16 + quad * 4 + r;
      int col = n0 + n * 16 + l16;
      float v = acc[n][r] * scale;
      if (Cf) Cf[(long)row * ldc + col] = v;
      if (Cb) Cb[(long)row * ldc + col] = f2bf(v);
    }
}

// ---------------- split-K GEMM for t1T (r13, + pack8) ----------------
__global__ __launch_bounds__(256)
void k_gemm_sk(const float* __restrict__ A, const float* __restrict__ B,
               float* __restrict__ Cf)
{
  const int n0 = blockIdx.x * 64, m0 = blockIdx.y * 64;
  const int kbase = blockIdx.z * 128;
  const int tid = threadIdx.x;
  const int wave = tid >> 6, lane = tid & 63, quad = lane >> 4, l16 = lane & 15;
  __shared__ u16 As[64 * 40];
  __shared__ u16 Bs[64 * 40];
  f32x4 acc[4];
#pragma unroll
  for (int n = 0; n < 4; ++n) acc[n] = (f32x4){0.f, 0.f, 0.f, 0.f};

  const int lr = tid >> 2;
  const int lc = (tid & 3) * 8;
  for (int k0 = kbase; k0 < kbase + 128; k0 += 32){
    {
      const float* pa = &A[(long)(m0 + lr) * 1024 + k0 + lc];
      *(short8*)&As[lr * 40 + lc] = pack8(*(const float4*)pa, *(const float4*)(pa + 4));
      const float* pb = &B[(long)(n0 + lr) * 1024 + k0 + lc];
      *(short8*)&Bs[lr * 40 + lc] = pack8(*(const float4*)pb, *(const float4*)(pb + 4));
    }
    __syncthreads();
    short8 a = *(const short8*)&As[(wave * 16 + l16) * 40 + quad * 8];
#pragma unroll
    for (int n = 0; n < 4; ++n){
      short8 b = *(const short8*)&Bs[(n * 16 + l16) * 40 + quad * 8];
      acc[n] = MFMA_BF16(a, b, acc[n], 0, 0, 0);
    }
    __syncthreads();
  }
#pragma unroll
  for (int n = 0; n < 4; ++n)
#pragma unroll
    for (int r = 0; r < 4; ++r){
      int row = m0 + wave * 16 + quad * 4 + r;
      int col = n0 + n * 16 + l16;
      atomicAdd(&Cf[(long)row * 256 + col], acc[n][r]);
    }
}

// ---------------- merged projections + vt GEMM (r13, + pack8) ----------------
__global__ __launch_bounds__(256)
void k_projv(const float* __restrict__ x, const float* __restrict__ Wdq,
             const float* __restrict__ Wdkv, u16* __restrict__ xq,
             float* __restrict__ ckv_f, u16* __restrict__ ckv_bf, u16* __restrict__ ckvT,
             const float* __restrict__ Wo, const float* __restrict__ wuvT,
             u16* __restrict__ vt)
{
  const int tid = threadIdx.x;
  const int wave = tid >> 6, lane = tid & 63, quad = lane >> 4, l16 = lane & 15;
  __shared__ u16 As[64 * 40];
  __shared__ u16 Bs[64 * 40];
  f32x4 acc[4];
#pragma unroll
  for (int n = 0; n < 4; ++n) acc[n] = (f32x4){0.f, 0.f, 0.f, 0.f};
  const int lr = tid >> 2;
  const int lc = (tid & 3) * 8;

  if (blockIdx.y >= 128){
    // ---- vt block: vt[1024,256] = bf16(Wo @ wuvT^T), tile t
    const int t = (blockIdx.y - 128) * 8 + blockIdx.x;   // 0..63
    const int m0 = (t >> 2) * 64, n0 = (t & 3) * 64;
    for (int k0 = 0; k0 < 1024; k0 += 32){
      {
        const float* pa = &Wo[(long)(m0 + lr) * 1024 + k0 + lc];
        *(short8*)&As[lr * 40 + lc] = pack8(*(const float4*)pa, *(const float4*)(pa + 4));
        const float* pb = &wuvT[(long)(n0 + lr) * 1024 + k0 + lc];
        *(short8*)&Bs[lr * 40 + lc] = pack8(*(const float4*)pb, *(const float4*)(pb + 4));
      }
      __syncthreads();
      short8 a = *(const short8*)&As[(wave * 16 + l16) * 40 + quad * 8];
#pragma unroll
      for (int n = 0; n < 4; ++n){
        short8 b = *(const short8*)&Bs[(n * 16 + l16) * 40 + quad * 8];
        acc[n] = MFMA_BF16(a, b, acc[n], 0, 0, 0);
      }
      __syncthreads();
    }
#pragma unroll
    for (int n = 0; n < 4; ++n)
#pragma unroll
      for (int r = 0; r < 4; ++r){
        int row = m0 + wave * 16 + quad * 4 + r;
        int col = n0 + n * 16 + l16;
        vt[(long)row * 256 + col] = f2bf(acc[n][r]);
      }
    return;
  }

  // ---- proj block (r7 k_proj body, chunked ckvT, pack8 staging)
  const bool is_kv = blockIdx.x >= 4;
  const float* B = is_kv ? Wdkv : Wdq;
  const int n0 = (blockIdx.x & 3) * 64, m0 = blockIdx.y * 64;
  for (int k0 = 0; k0 < 1024; k0 += 32){
    {
      const float* pa = &x[(long)(m0 + lr) * 1024 + k0 + lc];
      *(short8*)&As[lr * 40 + lc] = pack8(*(const float4*)pa, *(const float4*)(pa + 4));
      const float* pb = &B[(long)(n0 + lr) * 1024 + k0 + lc];
      *(short8*)&Bs[lr * 40 + lc] = pack8(*(const float4*)pb, *(const float4*)(pb + 4));
    }
    __syncthreads();
    short8 a = *(const short8*)&As[(wave * 16 + l16) * 40 + quad * 8];
#pragma unroll
    for (int n = 0; n < 4; ++n){
      short8 b = *(const short8*)&Bs[(n * 16 + l16) * 40 + quad * 8];
      acc[n] = MFMA_BF16(a, b, acc[n], 0, 0, 0);
    }
    __syncthreads();
  }
  if (!is_kv){
#pragma unroll
    for (int n = 0; n < 4; ++n)
#pragma unroll
      for (int r = 0; r < 4; ++r){
        int row = m0 + wave * 16 + quad * 4 + r;
        int col = n0 + n * 16 + l16;
        xq[(long)row * 256 + col] = f2bf(acc[n][r]);
      }
  } else {
    const int bb = (m0 >> 11);
    const long cbase = CKVT_OFF(bb);
    const int t0 = (m0 & 2047) + wave * 16 + quad * 4;
#pragma unroll
    for (int n = 0; n < 4; ++n){
      int col = n0 + n * 16 + l16;
      u16 pk[4];
#pragma unroll
      for (int r = 0; r < 4; ++r){
        int row = m0 + wave * 16 + quad * 4 + r;
        float v = acc[n][r];
        ckv_f [(long)row * 256 + col] = v;
        ckv_bf[(long)row * 256 + col] = f2bf(v);
        pk[r] = f2bf(v);
      }
      *(uint2*)&ckvT[cbase + (long)col * 2048 + t0] = *(uint2*)pk;
    }
  }
}

// ---------------- fused MLA flash attention (r7 body + chunked ckvT; best 486us) ----------------
__global__ __launch_bounds__(512, 2)
void k_flash(const u16* __restrict__ xq, const u16* __restrict__ Pt,
             const u16* __restrict__ ckv_bf, const u16* __restrict__ ckvT,
             const u16* __restrict__ Vt, float* __restrict__ y)
{
  const int bx = blockIdx.x;
  const int qt = (bx < 8) ? (15 - bx) : (bx - 8);   // XCD-balanced pairing
  const int h = blockIdx.y, b = blockIdx.z;
  const int tid = threadIdx.x;
  const int wg = tid >> 6, lane = tid & 63, quad = lane >> 4, l16 = lane & 15;

  __shared__ u16 LDS[73728];
  u16* PW = LDS + 65536 + wg * 1024;

  const int trow = wg * 16 + l16;
  const int swr  = l16 & 7;
  const long tglob = (long)b * 2048 + qt * 128;

  const u16* ckv_b  = ckv_bf + (long)b * 2048 * 256;
  const u16* ckvT_b = ckvT + CKVT_OFF(b);

  int offA[4], offB[4];
  {
    int l5 = lane >> 5, g32 = lane & 31;
#pragma unroll
    for (int j = 0; j < 4; ++j){
      int s = (wg * 4 + j) * 2 + l5;
      offA[j] = s * 256 + ((g32 ^ (s & 7)) * 8);
    }
    int l3 = lane >> 3, g8 = lane & 7;
#pragma unroll
    for (int j = 0; j < 4; ++j){
      int l = (wg * 4 + j) * 8 + l3;
      offB[j] = l * 2048 + ((g8 ^ (l & 7)) * 8);
    }
  }

  // ---- phase 0: q_lat^T = Pt[h](A) x xq(B); park in LDS[0..32768), read back aS
  short8 aS[8];
  {
    short8 bq[8];
    const u16* xr = xq + (tglob + trow) * 256;
#pragma unroll
    for (int ks = 0; ks < 8; ++ks)
      bq[ks] = *(const short8*)&xr[ks * 32 + quad * 8];
    const u16* pth = Pt + (long)h * 65536;
#pragma unroll
    for (int mb = 0; mb < 16; ++mb){
      f32x4 acc = (f32x4){0.f, 0.f, 0.f, 0.f};
#pragma unroll
      for (int ks = 0; ks < 8; ++ks){
        short8 pa = *(const short8*)&pth[(mb * 16 + l16) * 256 + ks * 32 + quad * 8];
        acc = MFMA_BF16(pa, bq[ks], acc, 0, 0, 0);
      }
#pragma unroll
      for (int r = 0; r < 4; ++r){
        int l = mb * 16 + quad * 4 + r;
        int cs = (((l >> 3) ^ swr) << 3) | (l & 7);
        LDS[trow * 256 + cs] = f2bf(acc[r]);
      }
    }
  }
  __syncthreads();
#pragma unroll
  for (int ks = 0; ks < 8; ++ks){
    int gl = ks * 4 + quad;
    aS[ks] = *(const short8*)&LDS[trow * 256 + ((gl ^ swr) << 3)];
  }
  __syncthreads();

  // prologue: stage tile 0 into buffer 0
#pragma unroll
  for (int j = 0; j < 4; ++j)
    gld16(ckv_b + offA[j], &LDS[(wg * 4 + j) * 512]);
#pragma unroll
  for (int j = 0; j < 4; ++j)
    gld16(ckvT_b + offB[j], &LDS[32768 + (wg * 4 + j) * 512]);

  // ---- phase 1: online-softmax KV loop (double-buffered, 1 barrier/iter)
  float m_t = -1e30f, l_t = 0.f;
  f32x4 oacc[16];
#pragma unroll
  for (int n = 0; n < 16; ++n) oacc[n] = (f32x4){0.f, 0.f, 0.f, 0.f};

  const int stmax = 2 * qt + 1;
  const int tg = qt * 128 + trow;
  for (int st = 0; st <= stmax; ++st){
    const int cur = st & 1;
    __syncthreads();
    if (st < stmax){
      const int nx = cur ^ 1;
#pragma unroll
      for (int j = 0; j < 4; ++j)
        gld16(ckv_b + (long)(st + 1) * 16384 + offA[j],
              &LDS[nx * 16384 + (wg * 4 + j) * 512]);
#pragma unroll
      for (int j = 0; j < 4; ++j)
        gld16(ckvT_b + (st + 1) * 64 + offB[j],
              &LDS[32768 + nx * 16384 + (wg * 4 + j) * 512]);
    }
    if (st * 64 > qt * 128 + wg * 16 + 15) continue;

    const u16* X0 = LDS + cur * 16384;
    const u16* X1 = LDS + 32768 + cur * 16384;

    f32x4 sacc[4];
#pragma unroll
    for (int mb = 0; mb < 4; ++mb) sacc[mb] = (f32x4){0.f, 0.f, 0.f, 0.f};
    __builtin_amdgcn_s_setprio(1);
#pragma unroll
    for (int ks = 0; ks < 8; ++ks){
      int gl = ks * 4 + quad;
#pragma unroll
      for (int mb = 0; mb < 4; ++mb){
        short8 a = *(const short8*)&X0[(mb * 16 + l16) * 256 + ((gl ^ swr) << 3)];
        sacc[mb] = MFMA_BF16(a, aS[ks], sacc[mb], 0, 0, 0);
      }
    }
    __builtin_amdgcn_s_setprio(0);

    if (st * 64 + 63 > tg){
#pragma unroll
      for (int mb = 0; mb < 4; ++mb)
#pragma unroll
        for (int r = 0; r < 4; ++r)
          if (st * 64 + mb * 16 + quad * 4 + r > tg) sacc[mb][r] = -1e30f;
    }

    float rm = sacc[0][0];
#pragma unroll
    for (int mb = 0; mb < 4; ++mb)
#pragma unroll
      for (int r = 0; r < 4; ++r) rm = fmaxf(rm, sacc[mb][r]);
    rm = fmaxf(rm, __shfl_xor(rm, 16, 64));
    rm = fmaxf(rm, __shfl_xor(rm, 32, 64));
    if (!__all(rm <= m_t + 8.f)){
      float mnew = fmaxf(m_t, rm);
      float alpha = __expf(m_t - mnew);
      m_t = mnew;
      l_t *= alpha;
#pragma unroll
      for (int r2 = 0; r2 < 4; ++r2){
        float ar = __shfl(alpha, quad * 4 + r2, 64);
#pragma unroll
        for (int n = 0; n < 16; ++n) oacc[n][r2] *= ar;
      }
    }
    float rs = 0.f;
#pragma unroll
    for (int mb = 0; mb < 4; ++mb){
      float p0 = __expf(sacc[mb][0] - m_t);
      float p1 = __expf(sacc[mb][1] - m_t);
      float p2 = __expf(sacc[mb][2] - m_t);
      float p3 = __expf(sacc[mb][3] - m_t);
      rs += (p0 + p1) + (p2 + p3);
      unsigned int w0 = (unsigned)f2bf(p0) | ((unsigned)f2bf(p1) << 16);
      unsigned int w1 = (unsigned)f2bf(p2) | ((unsigned)f2bf(p3) << 16);
      int pos = (2 * mb + (quad >> 1)) ^ swr;
      uint2 w; w.x = w0; w.y = w1;
      *(uint2*)&PW[l16 * 64 + pos * 8 + (quad & 1) * 4] = w;
    }
    rs += __shfl_xor(rs, 16, 64);
    rs += __shfl_xor(rs, 32, 64);
    l_t += rs;

    short8 a0 = *(const short8*)&PW[l16 * 64 + ((quad ^ swr) << 3)];
    short8 a1 = *(const short8*)&PW[l16 * 64 + (((4 + quad) ^ swr) << 3)];
    __builtin_amdgcn_s_setprio(1);
#pragma unroll
    for (int n = 0; n < 16; ++n){
      int lr_ = n * 16 + l16;
      int swl = lr_ & 7;
      short8 b0 = *(const short8*)&X1[lr_ * 64 + ((quad ^ swl) << 3)];
      short8 b1 = *(const short8*)&X1[lr_ * 64 + (((4 + quad) ^ swl) << 3)];
      oacc[n] = MFMA_BF16(a0, b0, oacc[n], 0, 0, 0);
      oacc[n] = MFMA_BF16(a1, b1, oacc[n], 0, 0, 0);
    }
    __builtin_amdgcn_s_setprio(0);
  }

  // ---- finalize: ctx = O / l -> park, y = ctx @ Vt
  __syncthreads();
  {
    float linv = 1.f / l_t;
#pragma unroll
    for (int r = 0; r < 4; ++r){
      float lr_ = __shfl(linv, quad * 4 + r, 64);
#pragma unroll
      for (int n = 0; n < 16; ++n) oacc[n][r] *= lr_;
    }
#pragma unroll
    for (int n = 0; n < 16; ++n)
#pragma unroll
      for (int r = 0; r < 4; ++r){
        int trw = wg * 16 + quad * 4 + r;
        int l = n * 16 + l16;
        int cs = (((l >> 3) ^ (trw & 7)) << 3) | (l & 7);
        LDS[trw * 256 + cs] = f2bf(oacc[n][r]);
      }
  }
  __syncthreads();
  {
    const u16* vth = Vt + (long)h * 64 * 256;
    short8 ca[8];
#pragma unroll
    for (int ks = 0; ks < 8; ++ks){
      int gl = ks * 4 + quad;
      ca[ks] = *(const short8*)&LDS[trow * 256 + ((gl ^ swr) << 3)];
    }
#pragma unroll
    for (int n = 0; n < 4; ++n){
      f32x4 acc = (f32x4){0.f, 0.f, 0.f, 0.f};
#pragma unroll
      for (int ks = 0; ks < 8; ++ks){
        short8 vb = *(const short8*)&vth[(n * 16 + l16) * 256 + ks * 32 + quad * 8];
        acc = MFMA_BF16(ca[ks], vb, acc, 0, 0, 0);
      }
#pragma unroll
      for (int r = 0; r < 4; ++r)
        y[(tglob + wg * 16 + quad * 4 + r) * 1024 + h * 64 + n * 16 + l16] = acc[r];
    }
  }
}

extern "C" void kernel_launch(void* const* d_in, const int* in_sizes, int n_in,
                              void* d_out, int out_size, void* d_ws, size_t ws_size,
                              hipStream_t stream)
{
  (void)in_sizes; (void)n_in; (void)out_size; (void)ws_size;
  const float* x    = (const float*)d_in[0];
  const float* Wdq  = (const float*)d_in[1];
  const float* Wuq  = (const float*)d_in[2];
  const float* Wdkv = (const float*)d_in[3];
  const float* Wuk  = (const float*)d_in[4];
  const float* Wuv  = (const float*)d_in[5];
  const float* Wo   = (const float*)d_in[6];

  float* y_out   = (float*)d_out;                      // (4,2048,1024) fp32
  float* ckv_out = y_out + (size_t)4 * 2048 * 1024;    // (4,2048,256) fp32

  char* base = (char*)d_ws;
  float* wdqT   = (float*)(base + 0);          // 1 MB, dead after keffT (g2)
  float* wuqT   = (float*)(base + 1048576);    // 1 MB, dead after pt (g3)
  float* wukT   = (float*)(base + 2097152);    // 1 MB, dead after t1T (g1)
  float* wuvT   = (float*)(base + 3145728);    // 1 MB, read by vt blocks in k_projv
  u16*   ckvT   = (u16*)  (base + 0);          // chunked: b0@0 b1@1M b2@2M b3@keffT
  float* t1T    = (float*)(base + 4194304);    // 256 KB
  float* keffT  = (float*)(base + 4456448);    // 1 MB, dead after g3 -> ckvT b3
  u16*   pt     = (u16*)  (base + 5505024);    // 2 MB (16,256,256)
  u16*   vt     = (u16*)  (base + 7602176);    // 512 KB (1024,256)
  u16*   xq     = (u16*)  (base + 8126464);    // 4 MB (8192,256)
  u16*   ckv_bf = (u16*)  (base + 12320768);   // 4 MB (4,2048,256) bf16

  // transposes + t1T zeroing (memset slot folded in)
  k_transpose4<<<dim3(32, 32, 4), dim3(32, 8), 0, stream>>>(
      Wdq, wdqT, Wuq, wuqT, Wuk, wukT, Wuv, wuvT, t1T);

  // g1 split-K x8: t1T += wukT @ wuqT^T
  k_gemm_sk<<<dim3(4, 4, 8), 256, 0, stream>>>(wukT, wuqT, t1T);

  k_gemm_nt<<<dim3(16, 4, 1), 256, 0, stream>>>(t1T, wdqT, keffT, (u16*)0,
      256, 1024, 256, 256, 256, 1024, 0, 0, 0, 1.f);
  k_gemm_nt<<<dim3(4, 4, 16), 256, 0, stream>>>(keffT, wuqT, (float*)0, pt,
      256, 256, 64, 1024, 1024, 256, 64, 64, 65536, 0.125f);

  // merged: proj (xq, ckv fp32/bf16/bf16-T chunked) + vt = Wo @ wuvT^T
  k_projv<<<dim3(8, 136), 256, 0, stream>>>(x, Wdq, Wdkv, xq, ckv_out, ckv_bf,
                                            ckvT, Wo, wuvT, vt);

  k_flash<<<dim3(16, 16, 4), 512, 0, stream>>>(xq, pt, ckv_bf, ckvT, vt, y_out);
}